// Round 9
// baseline (118.776 us; speedup 1.0000x reference)
//
#include <hip/hip_runtime.h>
#include <stdint.h>

#define B_   16
#define CIN  4
#define COUT 8
#define H_   512
#define W_   512
#define HP   (H_ + 2)
#define WP   (W_ + 2)
#define PMAX 756
#define TBL  (2 * PMAX + 1)
#define RPB  8                    // output rows per block
#define GY   (H_ / RPB)           // 64
#define NBLK (2 * GY * B_)        // 2048 blocks
#define LCOL 264                  // LDS row stride (258 used)

__device__ __forceinline__ int dot4(uint32_t a, int b, int c) {
#if __has_builtin(__builtin_amdgcn_sdot4)
    return __builtin_amdgcn_sdot4((int)a, b, c, false);
#else
    int r = c;
#pragma unroll
    for (int i = 0; i < 4; ++i) {
        int av = (int)((a >> (8 * i)) & 0xFFu);
        int bv = ((int)(((uint32_t)b) << (24 - 8 * i))) >> 24;
        r += av * bv;
    }
    return r;
#endif
}

__device__ __forceinline__ int dot8(uint32_t a, int b, int c) {
#if __has_builtin(__builtin_amdgcn_sdot8)
    return __builtin_amdgcn_sdot8((int)a, b, c, false);
#else
    int r = c;
#pragma unroll
    for (int i = 0; i < 8; ++i) {
        int av = (int)((a >> (4 * i)) & 0xFu);
        int bv = ((int)(((uint32_t)b) << (28 - 4 * i))) >> 28;
        r += av * bv;
    }
    return r;
#endif
}

__device__ __forceinline__ float rfl_f(float v) {
    return __int_as_float(__builtin_amdgcn_readfirstlane(__float_as_int(v)));
}

__device__ __forceinline__ int wquant(const float* w, float s_w,
                                      int co, int ci, int tap) {
    const int kh = tap / 3, kw = tap % 3;
    float wv = w[((co * CIN + ci) * 3 + kh) * 3 + kw];
    float q  = rintf(__fdiv_rn(wv, s_w));
    q = fminf(fmaxf(q, -7.0f), 7.0f);
    return (int)q;
}

__device__ __forceinline__ uint32_t qpix(const float* __restrict__ x,
                                         float s_in, int b, int d, int c) {
    const size_t plane = (size_t)H_ * W_;
    const float* p = x + ((size_t)b * CIN) * plane + (size_t)d * W_ + c;
    uint32_t v = 0;
#pragma unroll
    for (int ci = 0; ci < CIN; ++ci) {
        float q = rintf(__fdiv_rn(p[ci * plane], s_in));
        q = fminf(fmaxf(q, 0.0f), 255.0f);
        v |= ((uint32_t)(int)q) << (8 * ci);
    }
    return v;
}

#define EXTROW(slot, v0, v1, v2)                                          \
    do {                                                                  \
        uint32_t lo = ((v0) & 0x0F0F0F0Fu) | (((v1) << 4) & 0xF0F0F0F0u); \
        uint32_t hi = (((v0) >> 4) & 0x0F0F0F0Fu) | ((v1) & 0xF0F0F0F0u); \
        cpA[slot][0] = lo & 0x33333333u;                                  \
        cpA[slot][1] = (lo >> 2) & 0x33333333u;                           \
        cpA[slot][2] = (hi)&0x33333333u;                                  \
        cpA[slot][3] = (hi >> 2) & 0x33333333u;                           \
        sgl[slot][0] = (v2)&0x03030303u;                                  \
        sgl[slot][1] = ((v2) >> 2) & 0x03030303u;                         \
        sgl[slot][2] = ((v2) >> 4) & 0x03030303u;                         \
        sgl[slot][3] = ((v2) >> 6) & 0x03030303u;                         \
    } while (0)

// Pin values into VGPRs; blocks LDS-remat/rerun of the extraction chains.
#define PIN3(a, b, c) asm volatile("" : "+v"(a), "+v"(b), "+v"(c))
#define PINSLOT(slot)                                                     \
    asm volatile("" : "+v"(cpA[slot][0]), "+v"(cpA[slot][1]),             \
                      "+v"(cpA[slot][2]), "+v"(cpA[slot][3]),             \
                      "+v"(sgl[slot][0]), "+v"(sgl[slot][1]),             \
                      "+v"(sgl[slot][2]), "+v"(sgl[slot][3]))

// Fused: quantize own 10x258 halo -> LDS, publish interior xq rows for pass
// 2, then absmax-conv from LDS with a register-resident operand ring.
// (256,4): VGPR cap 128 (not 64) so the ring + load pipeline stay in regs.
__global__ __launch_bounds__(256, 4) void quant_conv1(
        const float* __restrict__ x, const float* __restrict__ weight,
        const float* __restrict__ s_in_p, const float* __restrict__ s_w_p,
        uint32_t* __restrict__ xq, uint32_t* __restrict__ wq8,
        int* __restrict__ absmax) {
    __shared__ uint32_t lds[10][LCOL];
    __shared__ uint32_t wlds[40];
    __shared__ int      red[4];
    const int t = threadIdx.x;

    const int raw = blockIdx.x;
    const int lin = (raw & 7) * (NBLK / 8) + (raw >> 3);
    const int bx = lin & 1;
    const int hy = (lin >> 1) & (GY - 1);
    const int b  = lin >> 7;
    const int w0 = bx * 256;
    const int h0 = hy * RPB;

    const float s_in = *s_in_p;

    if (t < 40) {   // weight quantization (block raw==0 publishes for pass 2)
        const float s_w = *s_w_p;
        uint32_t v = 0;
        if (t < 32) {
            const int co = t >> 2, p = t & 3;
            const int tA = (p == 0) ? 0 : (p == 1) ? 3 : (p == 2) ? 6 : 2;
            const int tB = (p == 0) ? 1 : (p == 1) ? 4 : (p == 2) ? 7 : 5;
#pragma unroll
            for (int ci = 0; ci < CIN; ++ci) {
                v |= ((uint32_t)(wquant(weight, s_w, co, ci, tA) & 0xF)) << (8 * ci);
                v |= ((uint32_t)(wquant(weight, s_w, co, ci, tB) & 0xF)) << (8 * ci + 4);
            }
        } else {
            const int co = t - 32;
#pragma unroll
            for (int ci = 0; ci < CIN; ++ci)
                v |= ((uint32_t)(wquant(weight, s_w, co, ci, 8) & 0xFF)) << (8 * ci);
        }
        wlds[t] = v;
        if (raw == 0) wq8[t] = v;
    }

    // halo quant: fully unrolled so the 40 loads pipeline
#pragma unroll
    for (int r = 0; r < 10; ++r) {
        const int d = h0 - 1 + r;
        const bool rowok = ((unsigned)d < (unsigned)H_);
        const int c = w0 - 1 + t;
        uint32_t v = 0;
        if (rowok && (unsigned)c < (unsigned)W_) v = qpix(x, s_in, b, d, c);
        lds[r][t] = v;
        if (t < 2) {
            const int c2 = w0 + 255 + t;
            uint32_t v2 = 0;
            if (rowok && (unsigned)c2 < (unsigned)W_) v2 = qpix(x, s_in, b, d, c2);
            lds[r][256 + t] = v2;
        }
    }
    __syncthreads();

    // publish interior xq rows + border zeros (for pass 2)
    {
        uint32_t* xb = xq + (size_t)b * HP * WP;
#pragma unroll
        for (int r = 1; r <= 8; ++r)
            xb[(size_t)(h0 + r) * WP + (w0 + 1 + t)] = lds[r][t + 1];
        if (hy == 0)
            for (int i = t; i < WP; i += 256) xb[i] = 0;
        if (hy == GY - 1)
            for (int i = t; i < WP; i += 256) xb[(size_t)(HP - 1) * WP + i] = 0;
        if (t == 0) {
            const int col = (bx == 0) ? 0 : (WP - 1);
#pragma unroll
            for (int r = 1; r <= 8; ++r) xb[(size_t)(h0 + r) * WP + col] = 0;
        }
    }

    // weights -> SGPRs
    int w8s[32], w4s[8];
#pragma unroll
    for (int i = 0; i < 32; ++i)
        w8s[i] = __builtin_amdgcn_readfirstlane((int)wlds[i]);
#pragma unroll
    for (int i = 0; i < 8; ++i)
        w4s[i] = __builtin_amdgcn_readfirstlane((int)wlds[32 + i]);

    // conv from LDS with pinned register ring (each LDS word read ONCE)
    uint32_t cpA[4][4], sgl[4][4];
    {
        uint32_t r0 = lds[0][t], r1 = lds[0][t + 1], r2 = lds[0][t + 2];
        PIN3(r0, r1, r2);
        EXTROW(0, r0, r1, r2);
        PINSLOT(0);
        r0 = lds[1][t]; r1 = lds[1][t + 1]; r2 = lds[1][t + 2];
        PIN3(r0, r1, r2);
        EXTROW(1, r0, r1, r2);
        PINSLOT(1);
    }

    int runMax = 0, runMin = 0;
#pragma unroll
    for (int s = 0; s < RPB; ++s) {
        {
            uint32_t r0 = lds[s + 2][t], r1 = lds[s + 2][t + 1],
                     r2 = lds[s + 2][t + 2];
            PIN3(r0, r1, r2);
            EXTROW((s + 2) & 3, r0, r1, r2);
        }
        PINSLOT((s + 2) & 3);
        const int m0 = s & 3, m1 = (s + 1) & 3, m2 = (s + 2) & 3;
        uint32_t pc[4];
#pragma unroll
        for (int k = 0; k < 4; ++k) pc[k] = sgl[m0][k] | (sgl[m1][k] << 4);
        asm volatile("" : "+v"(pc[0]), "+v"(pc[1]), "+v"(pc[2]), "+v"(pc[3]));
#pragma unroll
        for (int co = 0; co < COUT; ++co) {
#pragma unroll
            for (int k = 0; k < 4; ++k) {
                int a = dot4(sgl[m2][k], w4s[co], 0);
                a = dot8(cpA[m0][k], w8s[co * 4 + 0], a);
                a = dot8(cpA[m1][k], w8s[co * 4 + 1], a);
                a = dot8(cpA[m2][k], w8s[co * 4 + 2], a);
                a = dot8(pc[k],      w8s[co * 4 + 3], a);
                runMax = max(runMax, a);
                runMin = min(runMin, a);
            }
        }
    }

    int m = max(runMax, -runMin);
#pragma unroll
    for (int off = 1; off < 64; off <<= 1)
        m = max(m, __shfl_xor(m, off));
    if ((t & 63) == 0) red[t >> 6] = m;
    __syncthreads();
    if (t == 0) {
        int mm = max(max(red[0], red[1]), max(red[2], red[3]));
        atomicMax(absmax, mm);
    }
}

// Pass 2: unchanged (measured ~19 us, at the 134 MB write floor)
__global__ __launch_bounds__(256, 8) void conv2_kernel(
        const uint32_t* __restrict__ xq, const uint32_t* __restrict__ wq8,
        const float* __restrict__ bias, const float* __restrict__ sp_in,
        const float* __restrict__ sp_w, const float* __restrict__ sp_out,
        int* __restrict__ absmax, float* __restrict__ out) {
    __shared__ float tbl[TBL];
    const int tid = threadIdx.x;

    int w8s[32], w4s[8];
    {
        const int4* q4 = (const int4*)wq8;
#pragma unroll
        for (int i = 0; i < 8; ++i) {
            int4 w4i = q4[i];
            w8s[4 * i + 0] = __builtin_amdgcn_readfirstlane(w4i.x);
            w8s[4 * i + 1] = __builtin_amdgcn_readfirstlane(w4i.y);
            w8s[4 * i + 2] = __builtin_amdgcn_readfirstlane(w4i.z);
            w8s[4 * i + 3] = __builtin_amdgcn_readfirstlane(w4i.w);
        }
        int4 a0 = q4[8], a1 = q4[9];
        w4s[0] = __builtin_amdgcn_readfirstlane(a0.x);
        w4s[1] = __builtin_amdgcn_readfirstlane(a0.y);
        w4s[2] = __builtin_amdgcn_readfirstlane(a0.z);
        w4s[3] = __builtin_amdgcn_readfirstlane(a0.w);
        w4s[4] = __builtin_amdgcn_readfirstlane(a1.x);
        w4s[5] = __builtin_amdgcn_readfirstlane(a1.y);
        w4s[6] = __builtin_amdgcn_readfirstlane(a1.z);
        w4s[7] = __builtin_amdgcn_readfirstlane(a1.w);
    }

    const float pabs = fmaxf((float)(*absmax), 1e-6f);
    const float c63  = 1.0f / 63.0f;
    float g = rintf(__fdiv_rn(127.0f, __fmul_rn(pabs, c63)));
    g = fminf(fmaxf(g, 1.0f), 255.0f);
    const float step = __fdiv_rn(1.0f, __fmul_rn(g, c63));
    for (int i = tid; i < TBL; i += 256) {
        float p = (float)(i - PMAX);
        float r = rintf(__fdiv_rn(p, step));
        r = fminf(fmaxf(r, -127.0f), 127.0f);
        tbl[i] = __fmul_rn(r, step);
    }
    const float scale = __fmul_rn(rfl_f(*sp_in), rfl_f(*sp_w));
    const float s_out = rfl_f(*sp_out);
    float br[COUT];
#pragma unroll
    for (int co = 0; co < COUT; ++co) br[co] = rfl_f(bias[co]);
    __syncthreads();

    const int raw = blockIdx.x;
    const int lin = (raw & 7) * (NBLK / 8) + (raw >> 3);
    const int bx = lin & 1;
    const int hy = (lin >> 1) & (GY - 1);
    const int b  = lin >> 7;
    const int w0 = bx * 256 + tid;
    const int h0 = hy * RPB;

    const uint32_t* base = xq + ((size_t)b * HP + h0) * WP + w0;
    const size_t plane = (size_t)H_ * W_;

    uint32_t cpA[4][4], sgl[4][4];
    {
        uint32_t r0 = base[0], r1 = base[1], r2 = base[2];
        EXTROW(0, r0, r1, r2);
        r0 = base[WP]; r1 = base[WP + 1]; r2 = base[WP + 2];
        EXTROW(1, r0, r1, r2);
    }
    uint32_t n0 = base[2 * WP], n1 = base[2 * WP + 1], n2 = base[2 * WP + 2];

#pragma unroll
    for (int s = 0; s < RPB; ++s) {
        EXTROW((s + 2) & 3, n0, n1, n2);
        if (s <= RPB - 2) {
            const uint32_t* nr = base + (size_t)(s + 3) * WP;
            n0 = nr[0]; n1 = nr[1]; n2 = nr[2];
        }
        const int m0 = s & 3, m1 = (s + 1) & 3, m2 = (s + 2) & 3;
        uint32_t pc[4];
#pragma unroll
        for (int k = 0; k < 4; ++k) pc[k] = sgl[m0][k] | (sgl[m1][k] << 4);

        float* orow = out + ((size_t)b * COUT * H_ + (size_t)(h0 + s)) * W_ + w0;
#pragma unroll
        for (int co = 0; co < COUT; ++co) {
            float of = 0.0f;
#pragma unroll
            for (int k = 0; k < 4; ++k) {
                int a = dot4(sgl[m2][k], w4s[co], 0);
                a = dot8(cpA[m0][k], w8s[co * 4 + 0], a);
                a = dot8(cpA[m1][k], w8s[co * 4 + 1], a);
                a = dot8(cpA[m2][k], w8s[co * 4 + 2], a);
                a = dot8(pc[k],      w8s[co * 4 + 3], a);
                const float v = tbl[a + PMAX];
                if (k == 0)      of = v;
                else if (k == 1) of = __fadd_rn(of, __fmul_rn(v, 4.0f));
                else if (k == 2) of = __fadd_rn(of, __fmul_rn(v, 16.0f));
                else             of = __fadd_rn(of, __fmul_rn(v, 64.0f));
            }
            float o = __fadd_rn(__fmul_rn(of, scale), br[co]);
            float q = rintf(__fdiv_rn(o, s_out));
            q = fminf(fmaxf(q, -127.0f), 127.0f);
            orow[(size_t)co * plane] = __fmul_rn(q, s_out);
        }
    }
}

extern "C" void kernel_launch(void* const* d_in, const int* in_sizes, int n_in,
                              void* d_out, int out_size, void* d_ws, size_t ws_size,
                              hipStream_t stream) {
    const float* x      = (const float*)d_in[0];
    const float* weight = (const float*)d_in[1];
    const float* bias   = (const float*)d_in[2];
    const float* s_in   = (const float*)d_in[3];
    const float* s_w    = (const float*)d_in[4];
    const float* s_out  = (const float*)d_in[5];
    float* out = (float*)d_out;

    int*      absmax = (int*)d_ws;
    uint32_t* wq8    = (uint32_t*)((char*)d_ws + 256);   // 40 u32
    uint32_t* xq     = (uint32_t*)((char*)d_ws + 1024);

    hipMemsetAsync(absmax, 0, sizeof(int), stream);

    quant_conv1<<<dim3(NBLK), dim3(256), 0, stream>>>(
        x, weight, s_in, s_w, xq, wq8, absmax);

    conv2_kernel<<<dim3(NBLK), dim3(256), 0, stream>>>(
        xq, wq8, bias, s_in, s_w, s_out, absmax, out);
}

// Round 10
// 99.038 us; speedup vs baseline: 1.1993x; 1.1993x over previous
//
#include <hip/hip_runtime.h>
#include <stdint.h>

#define B_   16
#define CIN  4
#define COUT 8
#define H_   512
#define W_   512
#define HP   (H_ + 2)
#define WP   (W_ + 2)
#define PMAX 756
#define TBL  (2 * PMAX + 1)
#define RPB  8                    // output rows per block
#define GY   (H_ / RPB)           // 64
#define NBLK (2 * GY * B_)        // 2048 blocks
#define NQ   (B_ * HP)            // 8224 quant blocks (div by 8)

__device__ __forceinline__ int dot4(uint32_t a, int b, int c) {
#if __has_builtin(__builtin_amdgcn_sdot4)
    return __builtin_amdgcn_sdot4((int)a, b, c, false);
#else
    int r = c;
#pragma unroll
    for (int i = 0; i < 4; ++i) {
        int av = (int)((a >> (8 * i)) & 0xFFu);
        int bv = ((int)(((uint32_t)b) << (24 - 8 * i))) >> 24;
        r += av * bv;
    }
    return r;
#endif
}

__device__ __forceinline__ int dot8(uint32_t a, int b, int c) {
#if __has_builtin(__builtin_amdgcn_sdot8)
    return __builtin_amdgcn_sdot8((int)a, b, c, false);
#else
    int r = c;
#pragma unroll
    for (int i = 0; i < 8; ++i) {
        int av = (int)((a >> (4 * i)) & 0xFu);
        int bv = ((int)(((uint32_t)b) << (28 - 4 * i))) >> 28;
        r += av * bv;
    }
    return r;
#endif
}

__device__ __forceinline__ float rfl_f(float v) {
    return __int_as_float(__builtin_amdgcn_readfirstlane(__float_as_int(v)));
}

__device__ __forceinline__ int wquant(const float* w, float s_w,
                                      int co, int ci, int tap) {
    const int kh = tap / 3, kw = tap % 3;
    float wv = w[((co * CIN + ci) * 3 + kh) * 3 + kw];
    float q  = rintf(__fdiv_rn(wv, s_w));
    q = fminf(fmaxf(q, -7.0f), 7.0f);
    return (int)q;
}

// Quant+pack activations; block raw==0 packs weights for pass 1/2.
__global__ __launch_bounds__(128) void quant_pack_kernel(
        const float* __restrict__ x, const float* __restrict__ weight,
        const float* __restrict__ s_in_p, const float* __restrict__ s_w_p,
        uint32_t* __restrict__ xq, uint32_t* __restrict__ wq8) {
    const int raw = blockIdx.x;
    const int lin = (raw & 7) * (NQ / 8) + (raw >> 3);
    const int b = lin / HP, hp = lin % HP;
    const int t = threadIdx.x;
    if (raw == 0) {
        const float s_w = *s_w_p;
        if (t < 32) {                        // nibble pairs (0,1)(3,4)(6,7)(2,5)
            const int co = t >> 2, p = t & 3;
            const int tA = (p == 0) ? 0 : (p == 1) ? 3 : (p == 2) ? 6 : 2;
            const int tB = (p == 0) ? 1 : (p == 1) ? 4 : (p == 2) ? 7 : 5;
            uint32_t v = 0;
#pragma unroll
            for (int ci = 0; ci < CIN; ++ci) {
                v |= ((uint32_t)(wquant(weight, s_w, co, ci, tA) & 0xF)) << (8 * ci);
                v |= ((uint32_t)(wquant(weight, s_w, co, ci, tB) & 0xF)) << (8 * ci + 4);
            }
            wq8[t] = v;
        } else if (t < 40) {                 // tap-8 bytes
            const int co = t - 32;
            uint32_t v = 0;
#pragma unroll
            for (int ci = 0; ci < CIN; ++ci)
                v |= ((uint32_t)(wquant(weight, s_w, co, ci, 8) & 0xFF)) << (8 * ci);
            wq8[32 + co] = v;
        }
    }
    uint32_t* dst = xq + ((size_t)b * HP + hp) * WP;
    if (hp == 0 || hp == HP - 1) {
        for (int i = t; i < WP; i += 128) dst[i] = 0;
        return;
    }
    const float s_in = *s_in_p;
    const int h = hp - 1;
    const size_t plane = (size_t)H_ * W_;
    const float* xr = x + ((size_t)b * CIN) * plane + (size_t)h * W_ + 4 * t;
    float4 v0 = *(const float4*)(xr);
    float4 v1 = *(const float4*)(xr + plane);
    float4 v2 = *(const float4*)(xr + 2 * plane);
    float4 v3 = *(const float4*)(xr + 3 * plane);
    uint32_t o0 = 0, o1 = 0, o2 = 0, o3 = 0;
#define QP(f, ci, oj)                                                  \
    { float q = rintf(__fdiv_rn((f), s_in));                           \
      q = fminf(fmaxf(q, 0.0f), 255.0f);                               \
      oj |= ((uint32_t)(int)q) << (8 * (ci)); }
    QP(v0.x, 0, o0) QP(v0.y, 0, o1) QP(v0.z, 0, o2) QP(v0.w, 0, o3)
    QP(v1.x, 1, o0) QP(v1.y, 1, o1) QP(v1.z, 1, o2) QP(v1.w, 1, o3)
    QP(v2.x, 2, o0) QP(v2.y, 2, o1) QP(v2.z, 2, o2) QP(v2.w, 2, o3)
    QP(v3.x, 3, o0) QP(v3.y, 3, o1) QP(v3.z, 3, o2) QP(v3.w, 3, o3)
#undef QP
    uint32_t* d = dst + 1 + 4 * t;
    d[0] = o0; d[1] = o1; d[2] = o2; d[3] = o3;
    if (t == 0) dst[0] = 0;
    if (t == 127) dst[WP - 1] = 0;
}

#define EXTROW(slot, v0, v1, v2)                                          \
    do {                                                                  \
        uint32_t lo = ((v0) & 0x0F0F0F0Fu) | (((v1) << 4) & 0xF0F0F0F0u); \
        uint32_t hi = (((v0) >> 4) & 0x0F0F0F0Fu) | ((v1) & 0xF0F0F0F0u); \
        cpA[slot][0] = lo & 0x33333333u;                                  \
        cpA[slot][1] = (lo >> 2) & 0x33333333u;                           \
        cpA[slot][2] = (hi)&0x33333333u;                                  \
        cpA[slot][3] = (hi >> 2) & 0x33333333u;                           \
        sgl[slot][0] = (v2)&0x03030303u;                                  \
        sgl[slot][1] = ((v2) >> 2) & 0x03030303u;                         \
        sgl[slot][2] = ((v2) >> 4) & 0x03030303u;                         \
        sgl[slot][3] = ((v2) >> 6) & 0x03030303u;                         \
    } while (0)

// Conv passes (round-7 structure: global rolling window, ring operands).
// PASS 1: per-k max/min accumulators (4 independent chains), ONE plain
// store per block into blkmax[] — NO device atomics.
// PASS 2: LUT + epilogue, unchanged.
template <int PASS>
__global__ __launch_bounds__(256, 8) void conv_tmpl(
        const uint32_t* __restrict__ xq, const uint32_t* __restrict__ wq8,
        const float* __restrict__ bias, const float* __restrict__ sp_in,
        const float* __restrict__ sp_w, const float* __restrict__ sp_out,
        const int* __restrict__ absmax, int* __restrict__ blkmax,
        float* __restrict__ out) {
    __shared__ float tbl[PASS == 2 ? TBL : 1];
    __shared__ int   red[PASS == 1 ? 4 : 1];
    const int tid = threadIdx.x;

    int w8s[32], w4s[8];
    {
        const int4* q4 = (const int4*)wq8;
#pragma unroll
        for (int i = 0; i < 8; ++i) {
            int4 w4i = q4[i];
            w8s[4 * i + 0] = __builtin_amdgcn_readfirstlane(w4i.x);
            w8s[4 * i + 1] = __builtin_amdgcn_readfirstlane(w4i.y);
            w8s[4 * i + 2] = __builtin_amdgcn_readfirstlane(w4i.z);
            w8s[4 * i + 3] = __builtin_amdgcn_readfirstlane(w4i.w);
        }
        int4 a0 = q4[8], a1 = q4[9];
        w4s[0] = __builtin_amdgcn_readfirstlane(a0.x);
        w4s[1] = __builtin_amdgcn_readfirstlane(a0.y);
        w4s[2] = __builtin_amdgcn_readfirstlane(a0.z);
        w4s[3] = __builtin_amdgcn_readfirstlane(a0.w);
        w4s[4] = __builtin_amdgcn_readfirstlane(a1.x);
        w4s[5] = __builtin_amdgcn_readfirstlane(a1.y);
        w4s[6] = __builtin_amdgcn_readfirstlane(a1.z);
        w4s[7] = __builtin_amdgcn_readfirstlane(a1.w);
    }

    float scale = 0.0f, s_out = 0.0f, br[COUT];
    if (PASS == 2) {
        const float pabs = fmaxf((float)(*absmax), 1e-6f);
        const float c63  = 1.0f / 63.0f;
        float g = rintf(__fdiv_rn(127.0f, __fmul_rn(pabs, c63)));
        g = fminf(fmaxf(g, 1.0f), 255.0f);
        const float step = __fdiv_rn(1.0f, __fmul_rn(g, c63));
        for (int i = tid; i < TBL; i += 256) {
            float p = (float)(i - PMAX);
            float r = rintf(__fdiv_rn(p, step));
            r = fminf(fmaxf(r, -127.0f), 127.0f);
            tbl[i] = __fmul_rn(r, step);
        }
        scale = __fmul_rn(rfl_f(*sp_in), rfl_f(*sp_w));
        s_out = rfl_f(*sp_out);
#pragma unroll
        for (int co = 0; co < COUT; ++co) br[co] = rfl_f(bias[co]);
        __syncthreads();
    }

    // bijective XCD swizzle: XCD k owns images {2k, 2k+1}
    const int raw = blockIdx.x;
    const int lin = (raw & 7) * (NBLK / 8) + (raw >> 3);
    const int bx = lin & 1;
    const int hy = (lin >> 1) & (GY - 1);
    const int b  = lin >> 7;
    const int w0 = bx * 256 + tid;
    const int h0 = hy * RPB;

    const uint32_t* base = xq + ((size_t)b * HP + h0) * WP + w0;
    const size_t plane = (size_t)H_ * W_;

    uint32_t cpA[4][4], sgl[4][4];
    {
        uint32_t r0 = base[0], r1 = base[1], r2 = base[2];
        EXTROW(0, r0, r1, r2);
        r0 = base[WP]; r1 = base[WP + 1]; r2 = base[WP + 2];
        EXTROW(1, r0, r1, r2);
    }
    uint32_t n0 = base[2 * WP], n1 = base[2 * WP + 1], n2 = base[2 * WP + 2];

    int rmax[4] = {0, 0, 0, 0}, rmin[4] = {0, 0, 0, 0};

#pragma unroll
    for (int s = 0; s < RPB; ++s) {
        EXTROW((s + 2) & 3, n0, n1, n2);
        if (s <= RPB - 2) {
            const uint32_t* nr = base + (size_t)(s + 3) * WP;
            n0 = nr[0]; n1 = nr[1]; n2 = nr[2];
        }
        const int m0 = s & 3, m1 = (s + 1) & 3, m2 = (s + 2) & 3;
        uint32_t pc[4];
#pragma unroll
        for (int k = 0; k < 4; ++k) pc[k] = sgl[m0][k] | (sgl[m1][k] << 4);

        float* orow = (PASS == 2)
            ? out + ((size_t)b * COUT * H_ + (size_t)(h0 + s)) * W_ + w0
            : (float*)0;

#pragma unroll
        for (int co = 0; co < COUT; ++co) {
            float of = 0.0f;
#pragma unroll
            for (int k = 0; k < 4; ++k) {
                int a = dot4(sgl[m2][k], w4s[co], 0);
                a = dot8(cpA[m0][k], w8s[co * 4 + 0], a);
                a = dot8(cpA[m1][k], w8s[co * 4 + 1], a);
                a = dot8(cpA[m2][k], w8s[co * 4 + 2], a);
                a = dot8(pc[k],      w8s[co * 4 + 3], a);
                if (PASS == 1) {
                    rmax[k] = max(rmax[k], a);   // 4 independent chains
                    rmin[k] = min(rmin[k], a);
                } else {
                    const float v = tbl[a + PMAX];
                    if (k == 0)      of = v;
                    else if (k == 1) of = __fadd_rn(of, __fmul_rn(v, 4.0f));
                    else if (k == 2) of = __fadd_rn(of, __fmul_rn(v, 16.0f));
                    else             of = __fadd_rn(of, __fmul_rn(v, 64.0f));
                }
            }
            if (PASS == 2) {
                float o = __fadd_rn(__fmul_rn(of, scale), br[co]);
                float q = rintf(__fdiv_rn(o, s_out));
                q = fminf(fmaxf(q, -127.0f), 127.0f);
                orow[(size_t)co * plane] = __fmul_rn(q, s_out);
            }
        }
    }

    if (PASS == 1) {
        int m = 0;
#pragma unroll
        for (int k = 0; k < 4; ++k) m = max(m, max(rmax[k], -rmin[k]));
#pragma unroll
        for (int off = 1; off < 64; off <<= 1)
            m = max(m, __shfl_xor(m, off));
        if ((tid & 63) == 0) red[tid >> 6] = m;
        __syncthreads();
        if (tid == 0) {
            // plain per-block store — no cross-XCD atomic contention
            blkmax[raw] = max(max(red[0], red[1]), max(red[2], red[3]));
        }
    }
}

// 1-block reduction: 2048 per-block maxima -> *absmax (plain store).
__global__ __launch_bounds__(256) void reduce_absmax(
        const int* __restrict__ blkmax, int* __restrict__ absmax) {
    __shared__ int red[4];
    const int t = threadIdx.x;
    int m = 0;
#pragma unroll
    for (int i = 0; i < NBLK / 256; ++i) m = max(m, blkmax[t + 256 * i]);
#pragma unroll
    for (int off = 1; off < 64; off <<= 1)
        m = max(m, __shfl_xor(m, off));
    if ((t & 63) == 0) red[t >> 6] = m;
    __syncthreads();
    if (t == 0)
        *absmax = max(max(red[0], red[1]), max(red[2], red[3]));
}

extern "C" void kernel_launch(void* const* d_in, const int* in_sizes, int n_in,
                              void* d_out, int out_size, void* d_ws, size_t ws_size,
                              hipStream_t stream) {
    const float* x      = (const float*)d_in[0];
    const float* weight = (const float*)d_in[1];
    const float* bias   = (const float*)d_in[2];
    const float* s_in   = (const float*)d_in[3];
    const float* s_w    = (const float*)d_in[4];
    const float* s_out  = (const float*)d_in[5];
    float* out = (float*)d_out;

    int*      absmax = (int*)d_ws;
    uint32_t* wq8    = (uint32_t*)((char*)d_ws + 256);    // 40 u32
    int*      blkmax = (int*)((char*)d_ws + 1024);        // 2048 ints
    uint32_t* xq     = (uint32_t*)((char*)d_ws + 16384);

    quant_pack_kernel<<<dim3(NQ), dim3(128), 0, stream>>>(
        x, weight, s_in, s_w, xq, wq8);

    conv_tmpl<1><<<dim3(NBLK), dim3(256), 0, stream>>>(
        xq, wq8, bias, s_in, s_w, s_out, absmax, blkmax, out);

    reduce_absmax<<<dim3(1), dim3(256), 0, stream>>>(blkmax, absmax);

    conv_tmpl<2><<<dim3(NBLK), dim3(256), 0, stream>>>(
        xq, wq8, bias, s_in, s_w, s_out, absmax, blkmax, out);
}